// Round 1
// baseline (485.994 us; speedup 1.0000x reference)
//
#include <hip/hip_runtime.h>
#include <hip/hip_bf16.h>
#include <cstdint>
#include <cstddef>

// B=2, S=2048, D=512, H=8, DK=64
#define BB 2
#define SS 2048
#define DD 512
#define HH 8
#define DKK 64

typedef __attribute__((ext_vector_type(8))) short bf16x8;   // 8 bf16 = 4 VGPRs
typedef __attribute__((ext_vector_type(4))) float f32x4;

__device__ __forceinline__ unsigned short f2bf(float f) {
    union { float f; unsigned u; } v; v.f = f;
    unsigned u = v.u;
    return (unsigned short)((u + 0x7fffu + ((u >> 16) & 1u)) >> 16);   // RNE
}
__device__ __forceinline__ unsigned pack2(float a, float b) {
    return (unsigned)f2bf(a) | ((unsigned)f2bf(b) << 16);
}

// ---------------------------------------------------------------------------
// Kernel 1: QKV projections.  out[m,n] = sum_k X[m,k] * W[n,k]  (NT GEMM)
// z=0 -> Q head-split [bh][s][dk] bf16 ; z=1 -> K same ; z=2 -> V^T [bh][dk][s]
// ---------------------------------------------------------------------------
__global__ __launch_bounds__(256) void k_proj_qkv(
    const float* __restrict__ qin, const float* __restrict__ kin, const float* __restrict__ vin,
    const float* __restrict__ wq,  const float* __restrict__ wk,  const float* __restrict__ wv,
    unsigned short* __restrict__ Qw, unsigned short* __restrict__ Kw, unsigned short* __restrict__ Vt)
{
    __shared__ unsigned short smem[5120];      // Al [64][40] + Bl [64][40], reused as T [64][72]
    unsigned short* Al = smem;
    unsigned short* Bl = smem + 2560;

    const int z = blockIdx.z;
    const float* X = (z == 0) ? qin : (z == 1) ? kin : vin;
    const float* W = (z == 0) ? wq  : (z == 1) ? wk  : wv;

    const int bm = blockIdx.x, bn = blockIdx.y;
    const int tid = threadIdx.x;
    const int w = tid >> 6, lane = tid & 63, quad = lane >> 4, l15 = lane & 15;
    const int sr = tid >> 2, sc = (tid & 3) * 8;

    f32x4 acc[4];
    #pragma unroll
    for (int i = 0; i < 4; ++i) acc[i] = (f32x4){0.f, 0.f, 0.f, 0.f};

    const float* ap = X + (size_t)(bm * 64 + sr) * DD + sc;
    const float* bp = W + (size_t)(bn * 64 + sr) * DD + sc;

    for (int k0 = 0; k0 < DD; k0 += 32) {
        float4 a0 = *(const float4*)(ap + k0);
        float4 a1 = *(const float4*)(ap + k0 + 4);
        float4 b0 = *(const float4*)(bp + k0);
        float4 b1 = *(const float4*)(bp + k0 + 4);
        uint4 av = make_uint4(pack2(a0.x,a0.y), pack2(a0.z,a0.w), pack2(a1.x,a1.y), pack2(a1.z,a1.w));
        uint4 bv = make_uint4(pack2(b0.x,b0.y), pack2(b0.z,b0.w), pack2(b1.x,b1.y), pack2(b1.z,b1.w));
        *(uint4*)&Al[sr * 40 + sc] = av;
        *(uint4*)&Bl[sr * 40 + sc] = bv;
        __syncthreads();
        bf16x8 a = *(const bf16x8*)&Al[(w * 16 + l15) * 40 + quad * 8];
        #pragma unroll
        for (int nt = 0; nt < 4; ++nt) {
            bf16x8 b = *(const bf16x8*)&Bl[(nt * 16 + l15) * 40 + quad * 8];
            acc[nt] = __builtin_amdgcn_mfma_f32_16x16x32_bf16(a, b, acc[nt], 0, 0, 0);
        }
        __syncthreads();
    }

    if (z < 2) {
        unsigned short* dst = z ? Kw : Qw;
        #pragma unroll
        for (int nt = 0; nt < 4; ++nt) {
            int n = bn * 64 + nt * 16 + l15;
            int h = n >> 6, dk = n & 63;
            #pragma unroll
            for (int rg = 0; rg < 4; ++rg) {
                int m = bm * 64 + w * 16 + quad * 4 + rg;
                int b = m >> 11, s = m & (SS - 1);
                dst[(((size_t)(b * HH + h) * SS + s) << 6) + dk] = f2bf(acc[nt][rg]);
            }
        }
    } else {
        // transpose through LDS, then contiguous 32B stores along s
        unsigned short* T = smem;   // [64][72]
        #pragma unroll
        for (int nt = 0; nt < 4; ++nt)
            #pragma unroll
            for (int rg = 0; rg < 4; ++rg)
                T[(w * 16 + quad * 4 + rg) * 72 + nt * 16 + l15] = f2bf(acc[nt][rg]);
        __syncthreads();
        int n = tid >> 2, s0 = (tid & 3) * 16;
        int ng = bn * 64 + n, h = ng >> 6, dk = ng & 63;
        int mg = bm * 64 + s0, b = mg >> 11, s = mg & (SS - 1);
        unsigned vals[8];
        #pragma unroll
        for (int i = 0; i < 8; ++i)
            vals[i] = (unsigned)T[(s0 + 2*i) * 72 + n] | ((unsigned)T[(s0 + 2*i + 1) * 72 + n] << 16);
        unsigned short* dp = Vt + ((size_t)(b * HH + h) * DKK + dk) * SS + s;
        ((uint4*)dp)[0] = make_uint4(vals[0], vals[1], vals[2], vals[3]);
        ((uint4*)dp)[1] = make_uint4(vals[4], vals[5], vals[6], vals[7]);
    }
}

// ---------------------------------------------------------------------------
// Kernel 2: fused attention per (b,h) x 64-row q-tile.
// Pass 1: online (max-free) softmax accumulate l and O = sum e*V.
// Pass 2: recompute scores, stream p = e/l to d_out (the 256 MB write).
// ---------------------------------------------------------------------------
__global__ __launch_bounds__(256) void k_attn(
    const unsigned short* __restrict__ Qw, const unsigned short* __restrict__ Kw,
    const unsigned short* __restrict__ Vt, unsigned short* __restrict__ AO,
    float* __restrict__ P)
{
    __shared__ unsigned short Pl[4][16][72];
    const int qt = blockIdx.x, bh = blockIdx.y;
    const int tid = threadIdx.x, w = tid >> 6, lane = tid & 63, quad = lane >> 4, l15 = lane & 15;

    const unsigned short* Qb = Qw + ((size_t)bh * SS + qt * 64 + w * 16) * DKK;
    const unsigned short* Kb = Kw + (size_t)bh * SS * DKK;
    const unsigned short* Vb = Vt + (size_t)bh * DKK * SS;

    bf16x8 qa0 = *(const bf16x8*)&Qb[l15 * DKK + quad * 8];
    bf16x8 qa1 = *(const bf16x8*)&Qb[l15 * DKK + 32 + quad * 8];

    f32x4 oacc[4];
    #pragma unroll
    for (int i = 0; i < 4; ++i) oacc[i] = (f32x4){0.f, 0.f, 0.f, 0.f};
    float lsum[4] = {0.f, 0.f, 0.f, 0.f};

    for (int kt = 0; kt < SS / 64; ++kt) {
        const unsigned short* Kt = Kb + (size_t)kt * 64 * DKK;
        f32x4 sa[4];
        #pragma unroll
        for (int i = 0; i < 4; ++i) sa[i] = (f32x4){0.f, 0.f, 0.f, 0.f};
        #pragma unroll
        for (int jt = 0; jt < 4; ++jt) {
            bf16x8 b0 = *(const bf16x8*)&Kt[(jt * 16 + l15) * DKK + quad * 8];
            bf16x8 b1 = *(const bf16x8*)&Kt[(jt * 16 + l15) * DKK + 32 + quad * 8];
            sa[jt] = __builtin_amdgcn_mfma_f32_16x16x32_bf16(qa0, b0, sa[jt], 0, 0, 0);
            sa[jt] = __builtin_amdgcn_mfma_f32_16x16x32_bf16(qa1, b1, sa[jt], 0, 0, 0);
        }
        float ev[4][4];
        #pragma unroll
        for (int jt = 0; jt < 4; ++jt)
            #pragma unroll
            for (int rg = 0; rg < 4; ++rg)
                ev[jt][rg] = __expf(sa[jt][rg] * 0.125f);
        #pragma unroll
        for (int rg = 0; rg < 4; ++rg) {
            float v = ev[0][rg] + ev[1][rg] + ev[2][rg] + ev[3][rg];
            v += __shfl_xor(v, 1);
            v += __shfl_xor(v, 2);
            v += __shfl_xor(v, 4);
            v += __shfl_xor(v, 8);
            lsum[rg] += v;
        }
        #pragma unroll
        for (int jt = 0; jt < 4; ++jt)
            #pragma unroll
            for (int rg = 0; rg < 4; ++rg)
                Pl[w][quad * 4 + rg][jt * 16 + l15] = f2bf(ev[jt][rg]);
        __syncthreads();
        bf16x8 pa0 = *(const bf16x8*)&Pl[w][l15][quad * 8];
        bf16x8 pa1 = *(const bf16x8*)&Pl[w][l15][32 + quad * 8];
        #pragma unroll
        for (int dt = 0; dt < 4; ++dt) {
            const unsigned short* Vp = Vb + (size_t)(dt * 16 + l15) * SS + kt * 64;
            bf16x8 v0 = *(const bf16x8*)&Vp[quad * 8];
            bf16x8 v1 = *(const bf16x8*)&Vp[32 + quad * 8];
            oacc[dt] = __builtin_amdgcn_mfma_f32_16x16x32_bf16(pa0, v0, oacc[dt], 0, 0, 0);
            oacc[dt] = __builtin_amdgcn_mfma_f32_16x16x32_bf16(pa1, v1, oacc[dt], 0, 0, 0);
        }
        __syncthreads();
    }

    float linv[4];
    #pragma unroll
    for (int rg = 0; rg < 4; ++rg) linv[rg] = 1.0f / lsum[rg];

    // attention output (pre out-proj), layout [b][s][h*64+dk] bf16
    const int b = bh >> 3, h = bh & 7;
    const int srow = qt * 64 + w * 16 + quad * 4;
    #pragma unroll
    for (int dt = 0; dt < 4; ++dt)
        #pragma unroll
        for (int rg = 0; rg < 4; ++rg)
            AO[((size_t)(b * SS + srow + rg) << 9) + h * 64 + dt * 16 + l15] =
                f2bf(oacc[dt][rg] * linv[rg]);

    // pass 2: recompute scores, write normalized p_attn (fp32)
    float* Pb = P + (((size_t)bh * SS + qt * 64 + w * 16 + quad * 4) << 11);
    for (int kt = 0; kt < SS / 64; ++kt) {
        const unsigned short* Kt = Kb + (size_t)kt * 64 * DKK;
        #pragma unroll
        for (int jt = 0; jt < 4; ++jt) {
            bf16x8 b0 = *(const bf16x8*)&Kt[(jt * 16 + l15) * DKK + quad * 8];
            bf16x8 b1 = *(const bf16x8*)&Kt[(jt * 16 + l15) * DKK + 32 + quad * 8];
            f32x4 sa = (f32x4){0.f, 0.f, 0.f, 0.f};
            sa = __builtin_amdgcn_mfma_f32_16x16x32_bf16(qa0, b0, sa, 0, 0, 0);
            sa = __builtin_amdgcn_mfma_f32_16x16x32_bf16(qa1, b1, sa, 0, 0, 0);
            #pragma unroll
            for (int rg = 0; rg < 4; ++rg)
                Pb[((size_t)rg << 11) + kt * 64 + jt * 16 + l15] =
                    __expf(sa[rg] * 0.125f) * linv[rg];
        }
    }
}

// ---------------------------------------------------------------------------
// Kernel 3: out = AO(bf16) @ Wo^T  -> d_out[0 : 4096*512] fp32
// ---------------------------------------------------------------------------
__global__ __launch_bounds__(256) void k_outproj(
    const unsigned short* __restrict__ AO, const float* __restrict__ Wo, float* __restrict__ Out)
{
    __shared__ unsigned short Al[64 * 40];
    __shared__ unsigned short Bl[64 * 40];
    const int bm = blockIdx.x, bn = blockIdx.y;
    const int tid = threadIdx.x, w = tid >> 6, lane = tid & 63, quad = lane >> 4, l15 = lane & 15;
    const int sr = tid >> 2, sc = (tid & 3) * 8;

    f32x4 acc[4];
    #pragma unroll
    for (int i = 0; i < 4; ++i) acc[i] = (f32x4){0.f, 0.f, 0.f, 0.f};

    const unsigned short* ap = AO + (size_t)(bm * 64 + sr) * DD + sc;
    const float* bp = Wo + (size_t)(bn * 64 + sr) * DD + sc;

    for (int k0 = 0; k0 < DD; k0 += 32) {
        uint4 av = *(const uint4*)(ap + k0);
        float4 b0 = *(const float4*)(bp + k0);
        float4 b1 = *(const float4*)(bp + k0 + 4);
        uint4 bv = make_uint4(pack2(b0.x,b0.y), pack2(b0.z,b0.w), pack2(b1.x,b1.y), pack2(b1.z,b1.w));
        *(uint4*)&Al[sr * 40 + sc] = av;
        *(uint4*)&Bl[sr * 40 + sc] = bv;
        __syncthreads();
        bf16x8 a = *(const bf16x8*)&Al[(w * 16 + l15) * 40 + quad * 8];
        #pragma unroll
        for (int nt = 0; nt < 4; ++nt) {
            bf16x8 b = *(const bf16x8*)&Bl[(nt * 16 + l15) * 40 + quad * 8];
            acc[nt] = __builtin_amdgcn_mfma_f32_16x16x32_bf16(a, b, acc[nt], 0, 0, 0);
        }
        __syncthreads();
    }
    #pragma unroll
    for (int nt = 0; nt < 4; ++nt)
        #pragma unroll
        for (int rg = 0; rg < 4; ++rg)
            Out[(size_t)(bm * 64 + w * 16 + quad * 4 + rg) * DD + bn * 64 + nt * 16 + l15] =
                acc[nt][rg];
}

extern "C" void kernel_launch(void* const* d_in, const int* in_sizes, int n_in,
                              void* d_out, int out_size, void* d_ws, size_t ws_size,
                              hipStream_t stream) {
    const float* q  = (const float*)d_in[0];
    const float* k  = (const float*)d_in[1];
    const float* v  = (const float*)d_in[2];
    const float* wq = (const float*)d_in[3];
    const float* wk = (const float*)d_in[4];
    const float* wv = (const float*)d_in[5];
    const float* wo = (const float*)d_in[6];

    const size_t elems = (size_t)BB * HH * SS * DKK;   // 2,097,152 bf16 per tensor
    unsigned short* Qw = (unsigned short*)d_ws;
    unsigned short* Kw = Qw + elems;
    unsigned short* Vt = Kw + elems;
    unsigned short* AO = Vt + elems;

    float* out = (float*)d_out;                         // [4096, 512]
    float* P   = out + (size_t)BB * SS * DD;            // [2,8,2048,2048]

    k_proj_qkv<<<dim3(64, 8, 3), 256, 0, stream>>>(q, k, v, wq, wk, wv, Qw, Kw, Vt);
    k_attn   <<<dim3(SS / 64, BB * HH), 256, 0, stream>>>(Qw, Kw, Vt, AO, P);
    k_outproj<<<dim3(64, 8), 256, 0, stream>>>(AO, wo, out);
}

// Round 3
// 485.287 us; speedup vs baseline: 1.0015x; 1.0015x over previous
//
#include <hip/hip_runtime.h>
#include <hip/hip_bf16.h>
#include <cstdint>
#include <cstddef>

// B=2, S=2048, D=512, H=8, DK=64
#define BB 2
#define SS 2048
#define DD 512
#define HH 8
#define DKK 64

typedef __attribute__((ext_vector_type(8))) short bf16x8;   // 8 bf16 = 4 VGPRs
typedef __attribute__((ext_vector_type(4))) float f32x4;

__device__ __forceinline__ unsigned short f2bf(float f) {
    union { float f; unsigned u; } v; v.f = f;
    unsigned u = v.u;
    return (unsigned short)((u + 0x7fffu + ((u >> 16) & 1u)) >> 16);   // RNE
}
__device__ __forceinline__ unsigned pack2(float a, float b) {
    return (unsigned)f2bf(a) | ((unsigned)f2bf(b) << 16);
}

typedef const __attribute__((address_space(1))) unsigned int* gp_t;
typedef __attribute__((address_space(3))) unsigned int* lp_t;
__device__ __forceinline__ void gload_lds16(const void* g, void* l) {
    __builtin_amdgcn_global_load_lds((gp_t)g, (lp_t)l, 16, 0, 0);
}

// ---------------------------------------------------------------------------
// Kernel 0: fp32 -> bf16 conversion of all inputs, into scratch (P-region).
// ---------------------------------------------------------------------------
__global__ __launch_bounds__(256) void k_cvt(
    const float* __restrict__ q, const float* __restrict__ k, const float* __restrict__ v,
    const float* __restrict__ wq, const float* __restrict__ wk, const float* __restrict__ wv,
    const float* __restrict__ wo, unsigned short* __restrict__ dst)
{
    const size_t NX = (size_t)BB * SS * DD;   // 2,097,152
    const size_t NW = (size_t)DD * DD;        // 262,144
    const int y = blockIdx.y;
    const float* src; unsigned short* d; int n;
    switch (y) {
        case 0: src = q;  d = dst;                 n = (int)NX; break;
        case 1: src = k;  d = dst + NX;            n = (int)NX; break;
        case 2: src = v;  d = dst + 2 * NX;        n = (int)NX; break;
        case 3: src = wq; d = dst + 3 * NX;        n = (int)NW; break;
        case 4: src = wk; d = dst + 3 * NX + NW;   n = (int)NW; break;
        case 5: src = wv; d = dst + 3 * NX + 2*NW; n = (int)NW; break;
        default: src = wo; d = dst + 3 * NX + 3*NW; n = (int)NW; break;
    }
    int idx = (blockIdx.x * 256 + threadIdx.x) * 8;
    if (idx >= n) return;
    float4 a = *(const float4*)(src + idx);
    float4 b = *(const float4*)(src + idx + 4);
    *(uint4*)(d + idx) = make_uint4(pack2(a.x,a.y), pack2(a.z,a.w), pack2(b.x,b.y), pack2(b.z,b.w));
}

// ---------------------------------------------------------------------------
// 64x64-tile bf16 NT GEMM body (BK=64, global_load_lds, XOR-swizzled LDS).
// C[m,n] = sum_k A[m,k]*W[n,k].  Epilogue by MODE:
//  0: Q (scale 1/8, head-split bf16)  1: K (head-split bf16)
//  2: V (transpose -> Vt [bh][dk][s]) 3: out-proj (fp32 row-major)
// ---------------------------------------------------------------------------
template <int MODE>
__global__ __launch_bounds__(256) void k_gemm64(
    const unsigned short* __restrict__ A, const unsigned short* __restrict__ W,
    unsigned short* __restrict__ dbf, float* __restrict__ df)
{
    __shared__ unsigned short smem[8192];   // Al [64][64] + Bl [64][64] (swizzled)
    const int bm = blockIdx.x, bn = blockIdx.y;
    const int tid = threadIdx.x, w = tid >> 6, lane = tid & 63, quad = lane >> 4, l15 = lane & 15;

    f32x4 acc[4];
    #pragma unroll
    for (int i = 0; i < 4; ++i) acc[i] = (f32x4){0.f, 0.f, 0.f, 0.f};

    for (int k0 = 0; k0 < DD; k0 += 64) {
        #pragma unroll
        for (int r = 0; r < 2; ++r) {
            int flat = r * 256 + tid;
            int row = flat >> 3, c = flat & 7, cs = c ^ (row & 7);
            gload_lds16(A + (size_t)(bm * 64 + row) * DD + k0 + cs * 8, &smem[flat * 8]);
        }
        #pragma unroll
        for (int r = 0; r < 2; ++r) {
            int flat = r * 256 + tid;
            int row = flat >> 3, c = flat & 7, cs = c ^ (row & 7);
            gload_lds16(W + (size_t)(bn * 64 + row) * DD + k0 + cs * 8, &smem[4096 + flat * 8]);
        }
        __syncthreads();
        int mrow = w * 16 + l15;
        bf16x8 a0 = *(const bf16x8*)&smem[(mrow * 8 + (quad ^ (mrow & 7))) * 8];
        bf16x8 a1 = *(const bf16x8*)&smem[(mrow * 8 + ((quad + 4) ^ (mrow & 7))) * 8];
        #pragma unroll
        for (int nt = 0; nt < 4; ++nt) {
            int nrow = nt * 16 + l15;
            bf16x8 b0 = *(const bf16x8*)&smem[4096 + (nrow * 8 + (quad ^ (nrow & 7))) * 8];
            bf16x8 b1 = *(const bf16x8*)&smem[4096 + (nrow * 8 + ((quad + 4) ^ (nrow & 7))) * 8];
            acc[nt] = __builtin_amdgcn_mfma_f32_16x16x32_bf16(a0, b0, acc[nt], 0, 0, 0);
            acc[nt] = __builtin_amdgcn_mfma_f32_16x16x32_bf16(a1, b1, acc[nt], 0, 0, 0);
        }
        __syncthreads();
    }

    if (MODE == 0 || MODE == 1) {
        const float sc = (MODE == 0) ? 0.125f : 1.0f;
        #pragma unroll
        for (int nt = 0; nt < 4; ++nt) {
            int n = bn * 64 + nt * 16 + l15;
            int h = n >> 6, dk = n & 63;
            #pragma unroll
            for (int rg = 0; rg < 4; ++rg) {
                int m = bm * 64 + w * 16 + quad * 4 + rg;
                int b = m >> 11, s = m & (SS - 1);
                dbf[(((size_t)(b * HH + h) * SS + s) << 6) + dk] = f2bf(acc[nt][rg] * sc);
            }
        }
    } else if (MODE == 2) {
        unsigned short* T = smem;   // [64][72] = 9216 B, fits in 16 KB
        #pragma unroll
        for (int nt = 0; nt < 4; ++nt)
            #pragma unroll
            for (int rg = 0; rg < 4; ++rg)
                T[(w * 16 + quad * 4 + rg) * 72 + nt * 16 + l15] = f2bf(acc[nt][rg]);
        __syncthreads();
        int n = tid >> 2, s0 = (tid & 3) * 16;
        int ng = bn * 64 + n, h = ng >> 6, dk = ng & 63;
        int mg = bm * 64 + s0, b = mg >> 11, s = mg & (SS - 1);
        unsigned vals[8];
        #pragma unroll
        for (int i = 0; i < 8; ++i)
            vals[i] = (unsigned)T[(s0 + 2*i) * 72 + n] | ((unsigned)T[(s0 + 2*i + 1) * 72 + n] << 16);
        unsigned short* dp = dbf + ((size_t)(b * HH + h) * DKK + dk) * SS + s;
        ((uint4*)dp)[0] = make_uint4(vals[0], vals[1], vals[2], vals[3]);
        ((uint4*)dp)[1] = make_uint4(vals[4], vals[5], vals[6], vals[7]);
    } else {
        #pragma unroll
        for (int nt = 0; nt < 4; ++nt)
            #pragma unroll
            for (int rg = 0; rg < 4; ++rg)
                df[(size_t)(bm * 64 + w * 16 + quad * 4 + rg) * DD + bn * 64 + nt * 16 + l15] =
                    acc[nt][rg];
    }
}

// ---------------------------------------------------------------------------
// Kernel 2: attention core (pass 1 only). Q pre-scaled by 1/8.
// Per-wave private LDS (double-buffered, conflict-free stride 68) -> no barriers.
// Emits AO (bf16 [b][s][d]) and Linv (fp32 [bh][s]).
// ---------------------------------------------------------------------------
__global__ __launch_bounds__(256) void k_attn(
    const unsigned short* __restrict__ Qw, const unsigned short* __restrict__ Kw,
    const unsigned short* __restrict__ Vt, unsigned short* __restrict__ AO,
    float* __restrict__ Linv)
{
    __shared__ unsigned short Pl[2][4][16][68];
    const int qt = blockIdx.x, bh = blockIdx.y;
    const int tid = threadIdx.x, w = tid >> 6, lane = tid & 63, quad = lane >> 4, l15 = lane & 15;

    const unsigned short* Qb = Qw + ((size_t)bh * SS + qt * 64 + w * 16) * DKK;
    const unsigned short* Kb = Kw + (size_t)bh * SS * DKK;
    const unsigned short* Vb = Vt + (size_t)bh * DKK * SS;

    bf16x8 qa0 = *(const bf16x8*)&Qb[l15 * DKK + quad * 8];
    bf16x8 qa1 = *(const bf16x8*)&Qb[l15 * DKK + 32 + quad * 8];

    f32x4 oacc[4];
    #pragma unroll
    for (int i = 0; i < 4; ++i) oacc[i] = (f32x4){0.f, 0.f, 0.f, 0.f};
    float lsum[4] = {0.f, 0.f, 0.f, 0.f};

    #pragma unroll 2
    for (int kt = 0; kt < SS / 64; ++kt) {
        const int buf = kt & 1;
        const unsigned short* Kt = Kb + (size_t)kt * 64 * DKK;
        f32x4 sa[4];
        #pragma unroll
        for (int i = 0; i < 4; ++i) sa[i] = (f32x4){0.f, 0.f, 0.f, 0.f};
        #pragma unroll
        for (int jt = 0; jt < 4; ++jt) {
            bf16x8 b0 = *(const bf16x8*)&Kt[(jt * 16 + l15) * DKK + quad * 8];
            bf16x8 b1 = *(const bf16x8*)&Kt[(jt * 16 + l15) * DKK + 32 + quad * 8];
            sa[jt] = __builtin_amdgcn_mfma_f32_16x16x32_bf16(qa0, b0, sa[jt], 0, 0, 0);
            sa[jt] = __builtin_amdgcn_mfma_f32_16x16x32_bf16(qa1, b1, sa[jt], 0, 0, 0);
        }
        float ev[4][4];
        #pragma unroll
        for (int jt = 0; jt < 4; ++jt)
            #pragma unroll
            for (int rg = 0; rg < 4; ++rg)
                ev[jt][rg] = __expf(sa[jt][rg]);
        #pragma unroll
        for (int rg = 0; rg < 4; ++rg) {
            float s = ev[0][rg] + ev[1][rg] + ev[2][rg] + ev[3][rg];
            s += __shfl_xor(s, 1);
            s += __shfl_xor(s, 2);
            s += __shfl_xor(s, 4);
            s += __shfl_xor(s, 8);
            lsum[rg] += s;
        }
        #pragma unroll
        for (int jt = 0; jt < 4; ++jt)
            #pragma unroll
            for (int rg = 0; rg < 4; ++rg)
                Pl[buf][w][quad * 4 + rg][jt * 16 + l15] = f2bf(ev[jt][rg]);
        bf16x8 pa0 = *(const bf16x8*)&Pl[buf][w][l15][quad * 8];
        bf16x8 pa1 = *(const bf16x8*)&Pl[buf][w][l15][32 + quad * 8];
        #pragma unroll
        for (int dt = 0; dt < 4; ++dt) {
            const unsigned short* Vp = Vb + (size_t)(dt * 16 + l15) * SS + kt * 64;
            bf16x8 v0 = *(const bf16x8*)&Vp[quad * 8];
            bf16x8 v1 = *(const bf16x8*)&Vp[32 + quad * 8];
            oacc[dt] = __builtin_amdgcn_mfma_f32_16x16x32_bf16(pa0, v0, oacc[dt], 0, 0, 0);
            oacc[dt] = __builtin_amdgcn_mfma_f32_16x16x32_bf16(pa1, v1, oacc[dt], 0, 0, 0);
        }
    }

    float linv[4];
    #pragma unroll
    for (int rg = 0; rg < 4; ++rg) linv[rg] = 1.0f / lsum[rg];

    const int b = bh >> 3, h = bh & 7;
    const int srow = qt * 64 + w * 16 + quad * 4;
    #pragma unroll
    for (int dt = 0; dt < 4; ++dt)
        #pragma unroll
        for (int rg = 0; rg < 4; ++rg)
            AO[((size_t)(b * SS + srow + rg) << 9) + h * 64 + dt * 16 + l15] =
                f2bf(oacc[dt][rg] * linv[rg]);

    if (l15 == 0) {
        #pragma unroll
        for (int rg = 0; rg < 4; ++rg)
            Linv[(size_t)bh * SS + srow + rg] = linv[rg];
    }
}

// ---------------------------------------------------------------------------
// Kernel 3: p_attn writer. Recomputes scores (L2-hot K), streams 256 MB.
// grid (32 qtiles, 16 bh, 4 ksplit) = 2048 blocks.
// ---------------------------------------------------------------------------
__global__ __launch_bounds__(256) void k_pwrite(
    const unsigned short* __restrict__ Qw, const unsigned short* __restrict__ Kw,
    const float* __restrict__ Linv, float* __restrict__ P)
{
    const int qt = blockIdx.x, bh = blockIdx.y, ks = blockIdx.z;
    const int tid = threadIdx.x, w = tid >> 6, lane = tid & 63, quad = lane >> 4, l15 = lane & 15;

    const unsigned short* Qb = Qw + ((size_t)bh * SS + qt * 64 + w * 16) * DKK;
    bf16x8 qa0 = *(const bf16x8*)&Qb[l15 * DKK + quad * 8];
    bf16x8 qa1 = *(const bf16x8*)&Qb[l15 * DKK + 32 + quad * 8];

    float linv[4];
    #pragma unroll
    for (int rg = 0; rg < 4; ++rg)
        linv[rg] = Linv[(size_t)bh * SS + qt * 64 + w * 16 + quad * 4 + rg];

    const unsigned short* Kb = Kw + (size_t)bh * SS * DKK + (size_t)ks * 512 * DKK;
    float* Pb = P + (((size_t)bh * SS + qt * 64 + w * 16 + quad * 4) << 11) + ks * 512;

    for (int kt = 0; kt < 8; ++kt) {
        const unsigned short* Kt = Kb + (size_t)kt * 64 * DKK;
        #pragma unroll
        for (int jt = 0; jt < 4; ++jt) {
            bf16x8 b0 = *(const bf16x8*)&Kt[(jt * 16 + l15) * DKK + quad * 8];
            bf16x8 b1 = *(const bf16x8*)&Kt[(jt * 16 + l15) * DKK + 32 + quad * 8];
            f32x4 sa = (f32x4){0.f, 0.f, 0.f, 0.f};
            sa = __builtin_amdgcn_mfma_f32_16x16x32_bf16(qa0, b0, sa, 0, 0, 0);
            sa = __builtin_amdgcn_mfma_f32_16x16x32_bf16(qa1, b1, sa, 0, 0, 0);
            #pragma unroll
            for (int rg = 0; rg < 4; ++rg)
                Pb[((size_t)rg << 11) + kt * 64 + jt * 16 + l15] = __expf(sa[rg]) * linv[rg];
        }
    }
}

extern "C" void kernel_launch(void* const* d_in, const int* in_sizes, int n_in,
                              void* d_out, int out_size, void* d_ws, size_t ws_size,
                              hipStream_t stream) {
    const float* q  = (const float*)d_in[0];
    const float* k  = (const float*)d_in[1];
    const float* v  = (const float*)d_in[2];
    const float* wq = (const float*)d_in[3];
    const float* wk = (const float*)d_in[4];
    const float* wv = (const float*)d_in[5];
    const float* wo = (const float*)d_in[6];

    float* out = (float*)d_out;                         // [4096, 512] fp32
    float* P   = out + (size_t)BB * SS * DD;            // [2,8,2048,2048] fp32 (written last)

    // Scratch in the P region is ONLY read by kernels that complete before
    // k_pwrite launches (stream-ordered). Linv is read BY k_pwrite, so it
    // must NOT live in P -> it goes in d_ws.
    const size_t NX = (size_t)BB * SS * DD;   // 2,097,152
    const size_t NW = (size_t)DD * DD;        // 262,144
    unsigned short* scratch = (unsigned short*)P;
    unsigned short* Xq = scratch;
    unsigned short* Xk = scratch + NX;
    unsigned short* Xv = scratch + 2 * NX;
    unsigned short* Wq = scratch + 3 * NX;
    unsigned short* Wk = Wq + NW;
    unsigned short* Wv = Wk + NW;
    unsigned short* Wo = Wv + NW;
    unsigned short* AO = Wo + NW;               // read only by k_gemm64<3> (pre-k_pwrite)

    // d_ws: Q/K/V in attention layouts + Linv (12.125 MB)
    unsigned short* Qw = (unsigned short*)d_ws;
    unsigned short* Kw = Qw + NX;
    unsigned short* Vt = Kw + NX;
    float* Linv = (float*)(Vt + NX);            // [bh][s] fp32, 128 KB

    k_cvt<<<dim3(1024, 7), 256, 0, stream>>>(q, k, v, wq, wk, wv, wo, scratch);
    k_gemm64<0><<<dim3(64, 8), 256, 0, stream>>>(Xq, Wq, Qw, nullptr);
    k_gemm64<1><<<dim3(64, 8), 256, 0, stream>>>(Xk, Wk, Kw, nullptr);
    k_gemm64<2><<<dim3(64, 8), 256, 0, stream>>>(Xv, Wv, Vt, nullptr);
    k_attn<<<dim3(SS / 64, BB * HH), 256, 0, stream>>>(Qw, Kw, Vt, AO, Linv);
    k_gemm64<3><<<dim3(64, 8), 256, 0, stream>>>(AO, Wo, nullptr, out);
    k_pwrite<<<dim3(SS / 64, BB * HH, 4), 256, 0, stream>>>(Qw, Kw, Linv, P);
}